// Round 3
// baseline (78.578 us; speedup 1.0000x reference)
//
#include <hip/hip_runtime.h>
#include <math.h>

#define HWSZ 36864            // 192*192
#define NPIX 128              // pixels per block tile
#define NT2  288              // tiles per batch image
#define NBLK2 576             // total blocks (B=2)

typedef short bf16x8 __attribute__((ext_vector_type(8)));
typedef float f32x16 __attribute__((ext_vector_type(16)));
typedef unsigned int u32x4 __attribute__((ext_vector_type(4)));

__device__ __forceinline__ unsigned short f2bf(float x) {
    unsigned u = __float_as_uint(x);
    return (unsigned short)((u + 0x7fffu + ((u >> 16) & 1u)) >> 16);  // RNE
}

// ---------------- precompute 1: Dmat[s][d][c] = adapt_w[s][d][c] / sigma[s][d]
__global__ void pre_dmat(const float* __restrict__ aw, const float* __restrict__ sigma,
                         float* __restrict__ Dmat) {
    int idx = blockIdx.x * 256 + threadIdx.x;
    if (idx < 20480) {
        int sd = idx >> 6;
        Dmat[idx] = aw[idx] / sigma[sd];
    }
}

// ---------------- precompute 2: folded MLP weights (see round-2 derivation)
__global__ void pre_weights(const float* __restrict__ rw1, const float* __restrict__ rb1,
                            const float* __restrict__ ab, const float* __restrict__ mu,
                            const float* __restrict__ sigma, const float* __restrict__ Dmat,
                            float* __restrict__ MT, float* __restrict__ MSp,
                            float* __restrict__ c1) {
    int idx = blockIdx.x * 256 + threadIdx.x;
    if (idx < 20480) {
        int s = idx / 4096, r = idx % 4096, o = r >> 6, c = r & 63;
        float sum = 0.f;
        const float* wp = rw1 + o * 960 + s * 192;
        const float* D  = Dmat + s * 4096 + c;
        #pragma unroll 8
        for (int d = 0; d < 64; ++d)
            sum = fmaf(wp[64 + d] + wp[128 + d], D[d * 64], sum);
        MT[idx] = sum;                     // MT[s*4096 + o*64 + c]
    } else if (idx < 24576) {
        int k = idx - 20480;
        int o = k >> 6, c = k & 63;
        float sum = 0.f;
        for (int s = 0; s < 5; ++s) {
            const float* wp = rw1 + o * 960 + s * 192;
            const float* D  = Dmat + s * 4096 + c;
            #pragma unroll 8
            for (int d = 0; d < 64; ++d)
                sum = fmaf(wp[d] + wp[64 + d], D[d * 64], sum);
        }
        MSp[k] = sum;
    } else if (idx < 24640) {
        int o = idx - 24576;
        float sum = rb1[o];
        for (int s = 0; s < 5; ++s) {
            const float* wp = rw1 + o * 960 + s * 192;
            #pragma unroll 8
            for (int d = 0; d < 64; ++d) {
                int sd = s * 64 + d;
                sum = fmaf(wp[d] + wp[64 + d], (ab[sd] - mu[sd]) / sigma[sd], sum);
            }
        }
        c1[o] = sum;
    }
}

// ---------------- precompute 3: pack A-fragments (bf16) in MFMA 32x32x16 order
// AfragW layout [s][r(4)][t(4)][lane(64)][e(8)]; rows r<2 = D_s, r>=2 = MT_s
// AfragSp layout [r(2)][t(4)][lane(64)][e(8)] of MSp
__global__ void pre_pack(const float* __restrict__ Dmat, const float* __restrict__ MT,
                         const float* __restrict__ MSp,
                         unsigned short* __restrict__ AfragW,
                         unsigned short* __restrict__ AfragSp) {
    int i = blockIdx.x * 256 + threadIdx.x;
    if (i < 40960) {
        int s = i / 8192, rem = i % 8192;
        int r = rem / 2048, rem2 = rem % 2048;
        int t = rem2 / 512, q = rem2 % 512;
        int l = q >> 3, e = q & 7;
        int R = 32 * r + (l & 31);
        int k = 16 * t + 8 * (l >> 5) + e;
        float v = (R < 64) ? Dmat[s * 4096 + R * 64 + k] : MT[s * 4096 + (R - 64) * 64 + k];
        AfragW[i] = f2bf(v);
    } else if (i < 45056) {
        int j = i - 40960;
        int r = j / 2048, rem2 = j % 2048;
        int t = rem2 / 512, q = rem2 % 512;
        int l = q >> 3, e = q & 7;
        float v = MSp[(32 * r + (l & 31)) * 64 + 16 * t + 8 * (l >> 5) + e];
        AfragSp[j] = f2bf(v);
    }
}

// ---------------- fused main: 128-px tile, h in registers, async T staging
__global__ __launch_bounds__(256) void fused_main(
        const float* __restrict__ S, const float* __restrict__ T,
        const unsigned short* __restrict__ AfragW, const unsigned short* __restrict__ AfragSp,
        const float* __restrict__ c1, const float* __restrict__ rw2, const float* __restrict__ rb2,
        float* __restrict__ slearn, float* __restrict__ partial) {
    // X/S tiles [64][128] bf16, byte-swizzled: short idx = k*128 + (col ^ ((k&8)*4))
    __shared__ __align__(16) unsigned short bufA[8192];
    __shared__ __align__(16) unsigned short bufB[8192];
    __shared__ float w2s[320];
    __shared__ float c1s[64];
    __shared__ float rb2s[8];
    __shared__ float wred[5][4];

    const int tid  = threadIdx.x;
    const int lane = tid & 63;
    const int w    = tid >> 6;
    const int hi   = lane >> 5;
    const int px   = lane & 31;
    const int col  = (w << 5) + px;

    const int blk  = blockIdx.x;
    const int b    = blk / NT2;
    const int pix0 = (blk % NT2) * NPIX;

    for (int i = tid; i < 320; i += 256) w2s[i] = rw2[i];
    if (tid < 64) c1s[tid] = c1[tid];
    if (tid < 5)  rb2s[tid] = rb2[tid];

    // staging slice: thread handles rows c0, c0+32, pixel group pg*16..pg*16+15
    const int pg = tid & 7;
    const int c0 = tid >> 3;
    const float* Sbase = S + ((size_t)b * 64) * HWSZ + pix0 + pg * 16;
    const float* Tbase = T + ((size_t)(b * 5) * 64) * HWSZ + pix0 + pg * 16;

    // ---- load S slice (stays packed in regs), issue T0 ----
    float4 sldr[8];
    #pragma unroll
    for (int r = 0; r < 2; ++r) {
        const float* p = Sbase + (size_t)(c0 + 32 * r) * HWSZ;
        #pragma unroll
        for (int j = 0; j < 4; ++j) sldr[r * 4 + j] = *(const float4*)(p + 4 * j);
    }
    float4 tr[8];
    #pragma unroll
    for (int r = 0; r < 2; ++r) {
        const float* p = Tbase + (size_t)(c0 + 32 * r) * HWSZ;   // s = 0
        #pragma unroll
        for (int j = 0; j < 4; ++j) tr[r * 4 + j] = *(const float4*)(p + 4 * j);
    }

    // pack S -> sreg (bf16 pairs), write Sb tile to bufA
    u32x4 sreg[4];
    #pragma unroll
    for (int r = 0; r < 2; ++r) {
        const float4* v = sldr + 4 * r;
        unsigned o[8];
        #pragma unroll
        for (int q = 0; q < 4; ++q) {
            o[2 * q]     = (unsigned)f2bf(v[q].x) | ((unsigned)f2bf(v[q].y) << 16);
            o[2 * q + 1] = (unsigned)f2bf(v[q].z) | ((unsigned)f2bf(v[q].w) << 16);
        }
        u32x4 o0, o1;
        o0.x = o[0]; o0.y = o[1]; o0.z = o[2]; o0.w = o[3];
        o1.x = o[4]; o1.y = o[5]; o1.z = o[6]; o1.w = o[7];
        sreg[2 * r] = o0; sreg[2 * r + 1] = o1;
        int c = c0 + 32 * r;
        int flip = (c & 8) ? 32 : 0;
        unsigned short* dst = &bufA[c * 128 + ((pg * 16) ^ flip)];
        *(u32x4*)dst = o0;
        *(u32x4*)(dst + 8) = o1;
    }
    __syncthreads();

    // X_{s} = T_s - bf2f(S) -> bf16, write swizzled
    auto writeX = [&](unsigned short* buf) {
        #pragma unroll
        for (int r = 0; r < 2; ++r) {
            const float4* t = tr + 4 * r;
            float f[16];
            #pragma unroll
            for (int q = 0; q < 4; ++q) {
                f[4 * q] = t[q].x; f[4 * q + 1] = t[q].y;
                f[4 * q + 2] = t[q].z; f[4 * q + 3] = t[q].w;
            }
            unsigned spv[8];
            spv[0] = sreg[2 * r].x; spv[1] = sreg[2 * r].y; spv[2] = sreg[2 * r].z; spv[3] = sreg[2 * r].w;
            spv[4] = sreg[2 * r + 1].x; spv[5] = sreg[2 * r + 1].y; spv[6] = sreg[2 * r + 1].z; spv[7] = sreg[2 * r + 1].w;
            unsigned o[8];
            #pragma unroll
            for (int k = 0; k < 8; ++k) {
                float slo = __uint_as_float(spv[k] << 16);
                float shi = __uint_as_float(spv[k] & 0xffff0000u);
                unsigned short xlo = f2bf(f[2 * k] - slo);
                unsigned short xhi = f2bf(f[2 * k + 1] - shi);
                o[k] = (unsigned)xlo | ((unsigned)xhi << 16);
            }
            u32x4 o0, o1;
            o0.x = o[0]; o0.y = o[1]; o0.z = o[2]; o0.w = o[3];
            o1.x = o[4]; o1.y = o[5]; o1.z = o[6]; o1.w = o[7];
            int c = c0 + 32 * r;
            int flip = (c & 8) ? 32 : 0;
            unsigned short* dst = &buf[c * 128 + ((pg * 16) ^ flip)];
            *(u32x4*)dst = o0;
            *(u32x4*)(dst + 8) = o1;
        }
    };
    auto loadT = [&](int s) {
        #pragma unroll
        for (int r = 0; r < 2; ++r) {
            const float* p = Tbase + (size_t)(s * 64 + c0 + 32 * r) * HWSZ;
            #pragma unroll
            for (int j = 0; j < 4; ++j) tr[r * 4 + j] = *(const float4*)(p + 4 * j);
        }
    };

    f32x16 h0, h1;
    #pragma unroll
    for (int i = 0; i < 16; ++i) { h0[i] = 0.f; h1[i] = 0.f; }

    // ---- MSp @ S from bufA ----
    {
        const bf16x8* ap = (const bf16x8*)AfragSp + lane;
        #pragma unroll
        for (int kt = 0; kt < 4; ++kt) {
            int k0 = kt * 16 + hi * 8;
            int flip = hi ? 32 : 0;
            const unsigned short* bp = &bufA[k0 * 128 + (col ^ flip)];
            bf16x8 Bq;
            #pragma unroll
            for (int e = 0; e < 8; ++e) Bq[e] = (short)bp[e * 128];
            h0 = __builtin_amdgcn_mfma_f32_32x32x16_bf16(ap[(0 * 4 + kt) * 64], Bq, h0, 0, 0, 0);
            h1 = __builtin_amdgcn_mfma_f32_32x32x16_bf16(ap[(1 * 4 + kt) * 64], Bq, h1, 0, 0, 0);
        }
    }
    // X0 -> bufB (consumes T0), issue T1
    writeX(bufB);
    loadT(1);
    __syncthreads();

    #pragma unroll
    for (int s = 0; s < 5; ++s) {
        const unsigned short* cur = (s & 1) ? bufA : bufB;
        unsigned short* nxt       = (s & 1) ? bufB : bufA;
        const bf16x8* ap = (const bf16x8*)AfragW + (size_t)(s * 16) * 64 + lane;

        f32x16 d0, d1;
        #pragma unroll
        for (int i = 0; i < 16; ++i) { d0[i] = 0.f; d1[i] = 0.f; }

        #pragma unroll
        for (int kt = 0; kt < 4; ++kt) {
            int k0 = kt * 16 + hi * 8;
            int flip = hi ? 32 : 0;
            const unsigned short* bp = &cur[k0 * 128 + (col ^ flip)];
            bf16x8 Bq;
            #pragma unroll
            for (int e = 0; e < 8; ++e) Bq[e] = (short)bp[e * 128];
            d0 = __builtin_amdgcn_mfma_f32_32x32x16_bf16(ap[(0 * 4 + kt) * 64], Bq, d0, 0, 0, 0);
            d1 = __builtin_amdgcn_mfma_f32_32x32x16_bf16(ap[(1 * 4 + kt) * 64], Bq, d1, 0, 0, 0);
            h0 = __builtin_amdgcn_mfma_f32_32x32x16_bf16(ap[(2 * 4 + kt) * 64], Bq, h0, 0, 0, 0);
            h1 = __builtin_amdgcn_mfma_f32_32x32x16_bf16(ap[(3 * 4 + kt) * 64], Bq, h1, 0, 0, 0);
        }
        // proxy partial
        float sq = 0.f;
        #pragma unroll
        for (int i = 0; i < 16; ++i) {
            sq = fmaf(d0[i], d0[i], sq);
            sq = fmaf(d1[i], d1[i], sq);
        }
        #pragma unroll
        for (int m = 1; m < 64; m <<= 1) sq += __shfl_xor(sq, m, 64);
        if (lane == 0) wred[s][w] = sq;

        if (s < 4) {
            writeX(nxt);           // consumes T_{s+1} (vmcnt wait here)
            if (s < 3) loadT(s + 2);
        }
        __syncthreads();
    }

    if (tid < 5)
        partial[blk * 5 + tid] = wred[tid][0] + wred[tid][1] + wred[tid][2] + wred[tid][3];

    // epilogue: c1 + relu in regs, then score_learn = w2 @ relu(h) + b2
    #pragma unroll
    for (int i = 0; i < 16; ++i) {
        int row0 = (i & 3) + 8 * (i >> 2) + 4 * hi;
        h0[i] = fmaxf(h0[i] + c1s[row0], 0.f);
        h1[i] = fmaxf(h1[i] + c1s[row0 + 32], 0.f);
    }
    #pragma unroll
    for (int sp = 0; sp < 5; ++sp) {
        float acc = 0.f;
        #pragma unroll
        for (int i = 0; i < 16; ++i) {
            int row0 = (i & 3) + 8 * (i >> 2) + 4 * hi;
            acc = fmaf(w2s[sp * 64 + row0], h0[i], acc);
            acc = fmaf(w2s[sp * 64 + row0 + 32], h1[i], acc);
        }
        acc += __shfl_xor(acc, 32, 64);
        if (lane < 32)
            slearn[((size_t)(b * 5 + sp)) * HWSZ + pix0 + col] = acc + rb2s[sp];
    }
}

// ---------------- reduce proxy partials -> per-s score (deterministic)
__global__ void score_kernel(const float* __restrict__ partial,
                             const float* __restrict__ ema_proxy,
                             float* __restrict__ scoreBuf) {
    __shared__ float red[256];
    __shared__ float cur[5];
    int tid = threadIdx.x;
    for (int s = 0; s < 5; ++s) {
        float sum = 0.f;
        for (int i = tid; i < NBLK2; i += 256) sum += partial[i * 5 + s];
        red[tid] = sum;
        __syncthreads();
        for (int off = 128; off > 0; off >>= 1) {
            if (tid < off) red[tid] += red[tid + off];
            __syncthreads();
        }
        if (tid == 0) cur[s] = red[0] * (1.0f / (64.0f * 2.0f * HWSZ));
        __syncthreads();
    }
    if (tid == 0) {
        float impr[5]; float m = 0.f;
        for (int s = 0; s < 5; ++s) { impr[s] = ema_proxy[s] - cur[s]; m += impr[s]; }
        m *= 0.2f;
        for (int s = 0; s < 5; ++s) {
            float adv = impr[s] - m;
            float c = cur[s];
            float below = fmaxf(0.05f - c, 0.f);
            float above = fmaxf(c - 0.2f, 0.f);
            float band = -(below * below + above * above);
            scoreBuf[s] = 1.0f * adv + 0.5f * band;
        }
    }
}

// ---------------- per-pixel softmax over Sn=5
__global__ void softmax_kernel(const float* __restrict__ slearn,
                               const float* __restrict__ scoreBuf,
                               float* __restrict__ out) {
    int i = blockIdx.x * 256 + threadIdx.x;
    if (i >= 2 * HWSZ) return;
    int b = i / HWSZ, p = i % HWSZ;
    float l[5];
    float mx = -1e30f;
    #pragma unroll
    for (int s = 0; s < 5; ++s) {
        float v = (0.5f * scoreBuf[s] + 0.5f * slearn[((size_t)(b * 5 + s)) * HWSZ + p]) / 0.7f;
        l[s] = v;
        mx = fmaxf(mx, v);
    }
    float sum = 0.f;
    #pragma unroll
    for (int s = 0; s < 5; ++s) { l[s] = expf(l[s] - mx); sum += l[s]; }
    float inv = 1.0f / sum;
    #pragma unroll
    for (int s = 0; s < 5; ++s) out[((size_t)(b * 5 + s)) * HWSZ + p] = l[s] * inv;
}

extern "C" void kernel_launch(void* const* d_in, const int* in_sizes, int n_in,
                              void* d_out, int out_size, void* d_ws, size_t ws_size,
                              hipStream_t stream) {
    const float* S   = (const float*)d_in[0];
    const float* T   = (const float*)d_in[1];
    const float* aw  = (const float*)d_in[2];
    const float* ab  = (const float*)d_in[3];
    const float* rw1 = (const float*)d_in[4];
    const float* rb1 = (const float*)d_in[5];
    const float* rw2 = (const float*)d_in[6];
    const float* rb2 = (const float*)d_in[7];
    const float* mu  = (const float*)d_in[8];
    const float* sg  = (const float*)d_in[9];
    const float* ep  = (const float*)d_in[10];

    float* ws = (float*)d_ws;
    // persistent within launch:
    float* c1f      = ws;             // 64
    float* scoreBuf = ws + 64;        // 8
    float* partial  = ws + 72;        // 2880 (576*5)
    unsigned short* AfragW  = (unsigned short*)(ws + 5832);   // 40960 ush
    unsigned short* AfragSp = (unsigned short*)(ws + 26312);  // 4096 ush
    float* slearn   = ws + 28360;     // 368640
    // transient (dead before slearn is written) — aliased inside slearn region:
    float* Dmat     = ws + 28360;     // 20480
    float* MT       = ws + 48840;     // 20480
    float* MSp      = ws + 69320;     // 4096
    float* out = (float*)d_out;

    pre_dmat<<<80, 256, 0, stream>>>(aw, sg, Dmat);
    pre_weights<<<97, 256, 0, stream>>>(rw1, rb1, ab, mu, sg, Dmat, MT, MSp, c1f);
    pre_pack<<<176, 256, 0, stream>>>(Dmat, MT, MSp, AfragW, AfragSp);
    fused_main<<<NBLK2, 256, 0, stream>>>(S, T, AfragW, AfragSp, c1f, rw2, rb2, slearn, partial);
    score_kernel<<<1, 256, 0, stream>>>(partial, ep, scoreBuf);
    softmax_kernel<<<288, 256, 0, stream>>>(slearn, scoreBuf, out);
}

// Round 4
// 71.276 us; speedup vs baseline: 1.1025x; 1.1025x over previous
//
#include <hip/hip_runtime.h>
#include <math.h>

#define HWSZ 36864            // 192*192
#define NWID 2304             // fused blocks (1 wave / 32 px each)
#define PXW  32

typedef short bf16x8 __attribute__((ext_vector_type(8)));
typedef float f32x16 __attribute__((ext_vector_type(16)));
typedef unsigned int u32x4 __attribute__((ext_vector_type(4)));

__device__ __forceinline__ unsigned short f2bf(float x) {
    unsigned u = __float_as_uint(x);
    return (unsigned short)((u + 0x7fffu + ((u >> 16) & 1u)) >> 16);  // RNE
}

// ---------------- precompute 1: folded weights (Dmat inline), MT/MSp/c1/Dmat
__global__ void pre_weights(const float* __restrict__ rw1, const float* __restrict__ rb1,
                            const float* __restrict__ aw, const float* __restrict__ ab,
                            const float* __restrict__ mu, const float* __restrict__ sg,
                            float* __restrict__ Dmat, float* __restrict__ MT,
                            float* __restrict__ MSp, float* __restrict__ c1) {
    int idx = blockIdx.x * 256 + threadIdx.x;
    if (idx < 20480) {
        Dmat[idx] = aw[idx] / sg[idx >> 6];
        int s = idx / 4096, r = idx % 4096, o = r >> 6, c = r & 63;
        float sum = 0.f;
        const float* wp = rw1 + o * 960 + s * 192;
        const float* A  = aw + s * 4096 + c;
        const float* G  = sg + s * 64;
        #pragma unroll 8
        for (int d = 0; d < 64; ++d)
            sum = fmaf(wp[64 + d] + wp[128 + d], A[d * 64] / G[d], sum);
        MT[idx] = sum;                     // MT[s*4096 + o*64 + c]
    } else if (idx < 24576) {
        int k = idx - 20480;
        int o = k >> 6, c = k & 63;
        float sum = 0.f;
        for (int s = 0; s < 5; ++s) {
            const float* wp = rw1 + o * 960 + s * 192;
            const float* A  = aw + s * 4096 + c;
            const float* G  = sg + s * 64;
            #pragma unroll 8
            for (int d = 0; d < 64; ++d)
                sum = fmaf(wp[d] + wp[64 + d], A[d * 64] / G[d], sum);
        }
        MSp[k] = sum;
    } else if (idx < 24640) {
        int o = idx - 24576;
        float sum = rb1[o];
        for (int s = 0; s < 5; ++s) {
            const float* wp = rw1 + o * 960 + s * 192;
            #pragma unroll 8
            for (int d = 0; d < 64; ++d) {
                int sd = s * 64 + d;
                sum = fmaf(wp[d] + wp[64 + d], (ab[sd] - mu[sd]) / sg[sd], sum);
            }
        }
        c1[o] = sum;
    }
}

// ---------------- precompute 2: pack A-fragments (bf16) in MFMA 32x32x16 order
// AfragW layout [s][r(4)][t(4)][lane(64)][e(8)]; rows r<2 = D_s, r>=2 = MT_s
// AfragSp layout [r(2)][t(4)][lane(64)][e(8)] of MSp
__global__ void pre_pack(const float* __restrict__ Dmat, const float* __restrict__ MT,
                         const float* __restrict__ MSp,
                         unsigned short* __restrict__ AfragW,
                         unsigned short* __restrict__ AfragSp) {
    int i = blockIdx.x * 256 + threadIdx.x;
    if (i < 40960) {
        int s = i / 8192, rem = i % 8192;
        int r = rem / 2048, rem2 = rem % 2048;
        int t = rem2 / 512, q = rem2 % 512;
        int l = q >> 3, e = q & 7;
        int R = 32 * r + (l & 31);
        int k = 16 * t + 8 * (l >> 5) + e;
        float v = (R < 64) ? Dmat[s * 4096 + R * 64 + k] : MT[s * 4096 + (R - 64) * 64 + k];
        AfragW[i] = f2bf(v);
    } else if (i < 45056) {
        int j = i - 40960;
        int r = j / 2048, rem2 = j % 2048;
        int t = rem2 / 512, q = rem2 % 512;
        int l = q >> 3, e = q & 7;
        float v = MSp[(32 * r + (l & 31)) * 64 + 16 * t + 8 * (l >> 5) + e];
        AfragSp[j] = f2bf(v);
    }
}

// ---------------- fused main: 1 wave per 32-px tile, all data in registers
__global__ __launch_bounds__(64, 2) void fused_main(
        const float* __restrict__ S, const float* __restrict__ T,
        const unsigned short* __restrict__ AfragW, const unsigned short* __restrict__ AfragSp,
        const float* __restrict__ c1, const float* __restrict__ rw2, const float* __restrict__ rb2,
        float* __restrict__ slearn, float* __restrict__ partial) {
    __shared__ float w2s[320];
    __shared__ float c1s[64];
    __shared__ float rb2s[8];

    const int lane = threadIdx.x;
    const int hi = lane >> 5, px = lane & 31;
    const int wid = blockIdx.x;
    const int b = wid / 1152;
    const int pix0 = (wid % 1152) * PXW;

    for (int i = lane; i < 320; i += 64) w2s[i] = rw2[i];
    c1s[lane] = c1[lane];
    if (lane < 5) rb2s[lane] = rb2[lane];
    __syncthreads();

    // per-lane bases: lane owns pixel px, k-half hi (k = kt*16 + hi*8 + e)
    const float* Sb = S + ((size_t)b * 64 + hi * 8) * HWSZ + pix0 + px;
    const float* Tb = T + ((size_t)(b * 5 * 64) + hi * 8) * HWSZ + pix0 + px;

    // ---- S fragment: load 32 ch-values, pack bf16 B-frags ----
    float sv[32];
    #pragma unroll
    for (int i = 0; i < 32; ++i)
        sv[i] = Sb[(size_t)((i >> 3) * 16 + (i & 7)) * HWSZ];
    bf16x8 sf[4];
    #pragma unroll
    for (int kt = 0; kt < 4; ++kt) {
        union { bf16x8 h; u32x4 u; } U;
        #pragma unroll
        for (int j = 0; j < 4; ++j)
            U.u[j] = (unsigned)f2bf(sv[kt * 8 + 2 * j]) |
                     ((unsigned)f2bf(sv[kt * 8 + 2 * j + 1]) << 16);
        sf[kt] = U.h;
    }

    auto loadT = [&](float* tv, int s) {
        const float* p = Tb + (size_t)s * 64 * HWSZ;
        #pragma unroll
        for (int i = 0; i < 32; ++i)
            tv[i] = p[(size_t)((i >> 3) * 16 + (i & 7)) * HWSZ];
    };
    auto packX = [&](const float* tv, bf16x8* xf) {
        #pragma unroll
        for (int kt = 0; kt < 4; ++kt) {
            union { bf16x8 h; u32x4 u; } sU, xU;
            sU.h = sf[kt];
            #pragma unroll
            for (int j = 0; j < 4; ++j) {
                float slo = __uint_as_float(sU.u[j] << 16);
                float shi = __uint_as_float(sU.u[j] & 0xffff0000u);
                xU.u[j] = (unsigned)f2bf(tv[kt * 8 + 2 * j] - slo) |
                          ((unsigned)f2bf(tv[kt * 8 + 2 * j + 1] - shi) << 16);
            }
            xf[kt] = xU.h;
        }
    };

    f32x16 h0, h1;
    #pragma unroll
    for (int i = 0; i < 16; ++i) { h0[i] = 0.f; h1[i] = 0.f; }

    float tvA[32], tvB[32];
    loadT(tvA, 0);                       // T0 in flight under MSp GEMM

    // ---- MSp @ S ----
    {
        const bf16x8* asp = (const bf16x8*)AfragSp + lane;
        #pragma unroll
        for (int kt = 0; kt < 4; ++kt) {
            h0 = __builtin_amdgcn_mfma_f32_32x32x16_bf16(asp[kt * 64],       sf[kt], h0, 0, 0, 0);
            h1 = __builtin_amdgcn_mfma_f32_32x32x16_bf16(asp[(4 + kt) * 64], sf[kt], h1, 0, 0, 0);
        }
    }

    auto gemmS = [&](int s, const bf16x8* xf) {
        const bf16x8* aw = (const bf16x8*)AfragW + (size_t)s * 16 * 64 + lane;
        f32x16 d0, d1;
        #pragma unroll
        for (int i = 0; i < 16; ++i) { d0[i] = 0.f; d1[i] = 0.f; }
        #pragma unroll
        for (int kt = 0; kt < 4; ++kt) {
            d0 = __builtin_amdgcn_mfma_f32_32x32x16_bf16(aw[(0 * 4 + kt) * 64], xf[kt], d0, 0, 0, 0);
            d1 = __builtin_amdgcn_mfma_f32_32x32x16_bf16(aw[(1 * 4 + kt) * 64], xf[kt], d1, 0, 0, 0);
            h0 = __builtin_amdgcn_mfma_f32_32x32x16_bf16(aw[(2 * 4 + kt) * 64], xf[kt], h0, 0, 0, 0);
            h1 = __builtin_amdgcn_mfma_f32_32x32x16_bf16(aw[(3 * 4 + kt) * 64], xf[kt], h1, 0, 0, 0);
        }
        float sq = 0.f;
        #pragma unroll
        for (int i = 0; i < 16; ++i) {
            sq = fmaf(d0[i], d0[i], sq);
            sq = fmaf(d1[i], d1[i], sq);
        }
        #pragma unroll
        for (int m = 1; m < 64; m <<= 1) sq += __shfl_xor(sq, m, 64);
        if (lane == 0) partial[wid * 5 + s] = sq;
    };

    bf16x8 xf[4];
    packX(tvA, xf); loadT(tvB, 1); gemmS(0, xf);
    packX(tvB, xf); loadT(tvA, 2); gemmS(1, xf);
    packX(tvA, xf); loadT(tvB, 3); gemmS(2, xf);
    packX(tvB, xf); loadT(tvA, 4); gemmS(3, xf);
    packX(tvA, xf);                gemmS(4, xf);

    // ---- epilogue: relu(h + c1), score_learn = w2 @ relu(h) + b2 ----
    #pragma unroll
    for (int i = 0; i < 16; ++i) {
        int row0 = (i & 3) + 8 * (i >> 2) + 4 * hi;
        h0[i] = fmaxf(h0[i] + c1s[row0], 0.f);
        h1[i] = fmaxf(h1[i] + c1s[row0 + 32], 0.f);
    }
    #pragma unroll
    for (int sp = 0; sp < 5; ++sp) {
        float acc = 0.f;
        #pragma unroll
        for (int i = 0; i < 16; ++i) {
            int row0 = (i & 3) + 8 * (i >> 2) + 4 * hi;
            acc = fmaf(w2s[sp * 64 + row0],      h0[i], acc);
            acc = fmaf(w2s[sp * 64 + row0 + 32], h1[i], acc);
        }
        acc += __shfl_xor(acc, 32, 64);
        if (lane < 32)
            slearn[((size_t)(b * 5 + sp)) * HWSZ + pix0 + px] = acc + rb2s[sp];
    }
}

// ---------------- reduce proxy partials -> per-s score (deterministic)
__global__ void score_kernel(const float* __restrict__ partial,
                             const float* __restrict__ ema_proxy,
                             float* __restrict__ scoreBuf) {
    __shared__ float red[256];
    __shared__ float cur[5];
    int tid = threadIdx.x;
    for (int s = 0; s < 5; ++s) {
        float sum = 0.f;
        for (int i = tid; i < NWID; i += 256) sum += partial[i * 5 + s];
        red[tid] = sum;
        __syncthreads();
        for (int off = 128; off > 0; off >>= 1) {
            if (tid < off) red[tid] += red[tid + off];
            __syncthreads();
        }
        if (tid == 0) cur[s] = red[0] * (1.0f / (64.0f * 2.0f * HWSZ));
        __syncthreads();
    }
    if (tid == 0) {
        float impr[5]; float m = 0.f;
        for (int s = 0; s < 5; ++s) { impr[s] = ema_proxy[s] - cur[s]; m += impr[s]; }
        m *= 0.2f;
        for (int s = 0; s < 5; ++s) {
            float adv = impr[s] - m;
            float c = cur[s];
            float below = fmaxf(0.05f - c, 0.f);
            float above = fmaxf(c - 0.2f, 0.f);
            float band = -(below * below + above * above);
            scoreBuf[s] = 1.0f * adv + 0.5f * band;
        }
    }
}

// ---------------- per-pixel softmax over Sn=5
__global__ void softmax_kernel(const float* __restrict__ slearn,
                               const float* __restrict__ scoreBuf,
                               float* __restrict__ out) {
    int i = blockIdx.x * 256 + threadIdx.x;
    if (i >= 2 * HWSZ) return;
    int b = i / HWSZ, p = i % HWSZ;
    float l[5];
    float mx = -1e30f;
    #pragma unroll
    for (int s = 0; s < 5; ++s) {
        float v = (0.5f * scoreBuf[s] + 0.5f * slearn[((size_t)(b * 5 + s)) * HWSZ + p]) / 0.7f;
        l[s] = v;
        mx = fmaxf(mx, v);
    }
    float sum = 0.f;
    #pragma unroll
    for (int s = 0; s < 5; ++s) { l[s] = expf(l[s] - mx); sum += l[s]; }
    float inv = 1.0f / sum;
    #pragma unroll
    for (int s = 0; s < 5; ++s) out[((size_t)(b * 5 + s)) * HWSZ + p] = l[s] * inv;
}

extern "C" void kernel_launch(void* const* d_in, const int* in_sizes, int n_in,
                              void* d_out, int out_size, void* d_ws, size_t ws_size,
                              hipStream_t stream) {
    const float* S   = (const float*)d_in[0];
    const float* T   = (const float*)d_in[1];
    const float* aw  = (const float*)d_in[2];
    const float* ab  = (const float*)d_in[3];
    const float* rw1 = (const float*)d_in[4];
    const float* rb1 = (const float*)d_in[5];
    const float* rw2 = (const float*)d_in[6];
    const float* rb2 = (const float*)d_in[7];
    const float* mu  = (const float*)d_in[8];
    const float* sg  = (const float*)d_in[9];
    const float* ep  = (const float*)d_in[10];

    float* ws = (float*)d_ws;
    // persistent within launch:
    float* c1f      = ws;                                       // 64
    float* scoreBuf = ws + 64;                                  // 8
    float* partial  = ws + 72;                                  // 11520 (2304*5)
    unsigned short* AfragW  = (unsigned short*)(ws + 11592);    // 40960 ush = 20480 f
    unsigned short* AfragSp = (unsigned short*)(ws + 32072);    // 4096 ush = 2048 f
    float* slearn   = ws + 34120;                               // 368640
    // transient (dead before slearn is written) — aliased inside slearn region:
    float* Dmat     = ws + 34120;                               // 20480
    float* MT       = ws + 54600;                               // 20480
    float* MSp      = ws + 75080;                               // 4096
    float* out = (float*)d_out;

    pre_weights<<<97, 256, 0, stream>>>(rw1, rb1, aw, ab, mu, sg, Dmat, MT, MSp, c1f);
    pre_pack<<<176, 256, 0, stream>>>(Dmat, MT, MSp, AfragW, AfragSp);
    fused_main<<<NWID, 64, 0, stream>>>(S, T, AfragW, AfragSp, c1f, rw2, rb2, slearn, partial);
    score_kernel<<<1, 256, 0, stream>>>(partial, ep, scoreBuf);
    softmax_kernel<<<288, 256, 0, stream>>>(slearn, scoreBuf, out);
}

// Round 5
// 63.169 us; speedup vs baseline: 1.2439x; 1.1283x over previous
//
#include <hip/hip_runtime.h>
#include <math.h>

#define HWSZ 36864            // 192*192
#define NWID 2304             // fused blocks (1 wave / 32 px each)
#define PXW  32
#define LROW 36               // LDS row stride in u16 (pad 32 -> 36; 18 words, conflict-free gathers)

typedef short bf16x8 __attribute__((ext_vector_type(8)));
typedef float f32x16 __attribute__((ext_vector_type(16)));
typedef unsigned int u32x4 __attribute__((ext_vector_type(4)));

__device__ __forceinline__ unsigned short f2bf(float x) {
    unsigned u = __float_as_uint(x);
    return (unsigned short)((u + 0x7fffu + ((u >> 16) & 1u)) >> 16);  // RNE
}

// ---------------- precompute 1: folded weights (Dmat inline), MT/MSp/c1/Dmat
__global__ void pre_weights(const float* __restrict__ rw1, const float* __restrict__ rb1,
                            const float* __restrict__ aw, const float* __restrict__ ab,
                            const float* __restrict__ mu, const float* __restrict__ sg,
                            float* __restrict__ Dmat, float* __restrict__ MT,
                            float* __restrict__ MSp, float* __restrict__ c1) {
    int idx = blockIdx.x * 256 + threadIdx.x;
    if (idx < 20480) {
        Dmat[idx] = aw[idx] / sg[idx >> 6];
        int s = idx / 4096, r = idx % 4096, o = r >> 6, c = r & 63;
        float sum = 0.f;
        const float* wp = rw1 + o * 960 + s * 192;
        const float* A  = aw + s * 4096 + c;
        const float* G  = sg + s * 64;
        #pragma unroll 8
        for (int d = 0; d < 64; ++d)
            sum = fmaf(wp[64 + d] + wp[128 + d], A[d * 64] / G[d], sum);
        MT[idx] = sum;                     // MT[s*4096 + o*64 + c]
    } else if (idx < 24576) {
        int k = idx - 20480;
        int o = k >> 6, c = k & 63;
        float sum = 0.f;
        for (int s = 0; s < 5; ++s) {
            const float* wp = rw1 + o * 960 + s * 192;
            const float* A  = aw + s * 4096 + c;
            const float* G  = sg + s * 64;
            #pragma unroll 8
            for (int d = 0; d < 64; ++d)
                sum = fmaf(wp[d] + wp[64 + d], A[d * 64] / G[d], sum);
        }
        MSp[k] = sum;
    } else if (idx < 24640) {
        int o = idx - 24576;
        float sum = rb1[o];
        for (int s = 0; s < 5; ++s) {
            const float* wp = rw1 + o * 960 + s * 192;
            #pragma unroll 8
            for (int d = 0; d < 64; ++d) {
                int sd = s * 64 + d;
                sum = fmaf(wp[d] + wp[64 + d], (ab[sd] - mu[sd]) / sg[sd], sum);
            }
        }
        c1[o] = sum;
    }
}

// ---------------- precompute 2: pack A-fragments (bf16) in MFMA 32x32x16 order
// AfragW layout [s][r(4)][t(4)][lane(64)][e(8)]; rows r<2 = D_s, r>=2 = MT_s
// AfragSp layout [r(2)][t(4)][lane(64)][e(8)] of MSp
__global__ void pre_pack(const float* __restrict__ Dmat, const float* __restrict__ MT,
                         const float* __restrict__ MSp,
                         unsigned short* __restrict__ AfragW,
                         unsigned short* __restrict__ AfragSp) {
    int i = blockIdx.x * 256 + threadIdx.x;
    if (i < 40960) {
        int s = i / 8192, rem = i % 8192;
        int r = rem / 2048, rem2 = rem % 2048;
        int t = rem2 / 512, q = rem2 % 512;
        int l = q >> 3, e = q & 7;
        int R = 32 * r + (l & 31);
        int k = 16 * t + 8 * (l >> 5) + e;
        float v = (R < 64) ? Dmat[s * 4096 + R * 64 + k] : MT[s * 4096 + (R - 64) * 64 + k];
        AfragW[i] = f2bf(v);
    } else if (i < 45056) {
        int j = i - 40960;
        int r = j / 2048, rem2 = j % 2048;
        int t = rem2 / 512, q = rem2 % 512;
        int l = q >> 3, e = q & 7;
        float v = MSp[(32 * r + (l & 31)) * 64 + 16 * t + 8 * (l >> 5) + e];
        AfragSp[j] = f2bf(v);
    }
}

// ---------------- fused main: 1 wave / 32-px tile, wide loads + LDS transpose
__global__ __launch_bounds__(64, 4) void fused_main(
        const float* __restrict__ S, const float* __restrict__ T,
        const unsigned short* __restrict__ AfragW, const unsigned short* __restrict__ AfragSp,
        const float* __restrict__ c1, const float* __restrict__ rw2, const float* __restrict__ rb2,
        float* __restrict__ slearn, float* __restrict__ partial) {
    __shared__ __align__(16) unsigned short bufS[64 * LROW];
    __shared__ __align__(16) unsigned short bufA[64 * LROW];
    __shared__ __align__(16) unsigned short bufB[64 * LROW];
    __shared__ float w2s[320];
    __shared__ float c1s[64];
    __shared__ float rb2s[8];

    const int lane = threadIdx.x;
    const int hi = lane >> 5, px = lane & 31;
    const int wid = blockIdx.x;
    const int b = wid / 1152;
    const int pix0 = (wid % 1152) * PXW;

    // staging mapping: slot j -> channel chL+j, pixels pxg*4 .. pxg*4+3
    const int pxg = lane & 7;
    const int chL = (lane >> 3) * 8;
    const float* Sp = S + ((size_t)b * 64 + chL) * HWSZ + pix0 + pxg * 4;
    const float* Tp = T + ((size_t)(b * 5) * 64 + chL) * HWSZ + pix0 + pxg * 4;

    float4 R[8];

    // ---- prologue: S -> bufS (bf16), small weights -> LDS ----
    #pragma unroll
    for (int j = 0; j < 8; ++j) R[j] = *(const float4*)(Sp + (size_t)j * HWSZ);

    for (int i = lane; i < 320; i += 64) w2s[i] = rw2[i];
    c1s[lane] = c1[lane];
    if (lane < 5) rb2s[lane] = rb2[lane];

    #pragma unroll
    for (int j = 0; j < 8; ++j) {
        unsigned o0 = (unsigned)f2bf(R[j].x) | ((unsigned)f2bf(R[j].y) << 16);
        unsigned o1 = (unsigned)f2bf(R[j].z) | ((unsigned)f2bf(R[j].w) << 16);
        uint2* dp = (uint2*)&bufS[(chL + j) * LROW + pxg * 4];
        *dp = make_uint2(o0, o1);
    }

    // gather B-fragment (8 channels kt*16+hi*8.. for pixel px) from an LDS tile
    auto gatherB = [&](const unsigned short* buf, int kt) -> bf16x8 {
        const unsigned short* p = buf + (kt * 16 + hi * 8) * LROW + px;
        union { bf16x8 h; u32x4 u; } U;
        #pragma unroll
        for (int j = 0; j < 4; ++j)
            U.u[j] = (unsigned)p[(2 * j) * LROW] | ((unsigned)p[(2 * j + 1) * LROW] << 16);
        return U.h;
    };

    // X = T - bf16(S): pack R (T f32) minus bufS readback, write bf16 tile
    auto packX = [&](unsigned short* dst) {
        #pragma unroll
        for (int j = 0; j < 8; ++j) {
            const uint2* sp = (const uint2*)&bufS[(chL + j) * LROW + pxg * 4];
            uint2 sv = *sp;
            float s0 = __uint_as_float(sv.x << 16);
            float s1 = __uint_as_float(sv.x & 0xffff0000u);
            float s2 = __uint_as_float(sv.y << 16);
            float s3 = __uint_as_float(sv.y & 0xffff0000u);
            unsigned o0 = (unsigned)f2bf(R[j].x - s0) | ((unsigned)f2bf(R[j].y - s1) << 16);
            unsigned o1 = (unsigned)f2bf(R[j].z - s2) | ((unsigned)f2bf(R[j].w - s3) << 16);
            uint2* dp = (uint2*)&dst[(chL + j) * LROW + pxg * 4];
            *dp = make_uint2(o0, o1);
        }
    };
    auto loadT = [&](int s) {
        const float* p = Tp + (size_t)(s * 64) * HWSZ;
        #pragma unroll
        for (int j = 0; j < 8; ++j) R[j] = *(const float4*)(p + (size_t)j * HWSZ);
    };

    f32x16 h0, h1;
    #pragma unroll
    for (int i = 0; i < 16; ++i) { h0[i] = 0.f; h1[i] = 0.f; }

    loadT(0);                                  // T0 in flight under MSp GEMM

    // ---- MSp @ S (gather from bufS) ----
    {
        const bf16x8* asp = (const bf16x8*)AfragSp + lane;
        #pragma unroll
        for (int kt = 0; kt < 4; ++kt) {
            bf16x8 Bq = gatherB(bufS, kt);
            h0 = __builtin_amdgcn_mfma_f32_32x32x16_bf16(asp[kt * 64],       Bq, h0, 0, 0, 0);
            h1 = __builtin_amdgcn_mfma_f32_32x32x16_bf16(asp[(4 + kt) * 64], Bq, h1, 0, 0, 0);
        }
    }

    auto gemmS = [&](int s, const unsigned short* buf) {
        const bf16x8* aw2 = (const bf16x8*)AfragW + (size_t)(s * 16) * 64 + lane;
        f32x16 d0, d1;
        #pragma unroll
        for (int i = 0; i < 16; ++i) { d0[i] = 0.f; d1[i] = 0.f; }
        #pragma unroll
        for (int kt = 0; kt < 4; ++kt) {
            bf16x8 Bq = gatherB(buf, kt);
            d0 = __builtin_amdgcn_mfma_f32_32x32x16_bf16(aw2[(0 * 4 + kt) * 64], Bq, d0, 0, 0, 0);
            d1 = __builtin_amdgcn_mfma_f32_32x32x16_bf16(aw2[(1 * 4 + kt) * 64], Bq, d1, 0, 0, 0);
            h0 = __builtin_amdgcn_mfma_f32_32x32x16_bf16(aw2[(2 * 4 + kt) * 64], Bq, h0, 0, 0, 0);
            h1 = __builtin_amdgcn_mfma_f32_32x32x16_bf16(aw2[(3 * 4 + kt) * 64], Bq, h1, 0, 0, 0);
        }
        float sq = 0.f;
        #pragma unroll
        for (int i = 0; i < 16; ++i) {
            sq = fmaf(d0[i], d0[i], sq);
            sq = fmaf(d1[i], d1[i], sq);
        }
        #pragma unroll
        for (int m = 1; m < 64; m <<= 1) sq += __shfl_xor(sq, m, 64);
        if (lane == 0) partial[wid * 5 + s] = sq;
    };

    // ---- pipelined s-loop: loads for s+1 in flight under gemm(s) ----
    packX(bufA);                // X0 (waits T0)
    loadT(1);
    gemmS(0, bufA);
    packX(bufB);                // X1 (waits T1)
    loadT(2);
    gemmS(1, bufB);
    packX(bufA);                // X2
    loadT(3);
    gemmS(2, bufA);
    packX(bufB);                // X3
    loadT(4);
    gemmS(3, bufB);
    packX(bufA);                // X4
    gemmS(4, bufA);

    // ---- epilogue: relu(h + c1), score_learn = w2 @ relu(h) + b2 ----
    #pragma unroll
    for (int i = 0; i < 16; ++i) {
        int row0 = (i & 3) + 8 * (i >> 2) + 4 * hi;
        h0[i] = fmaxf(h0[i] + c1s[row0], 0.f);
        h1[i] = fmaxf(h1[i] + c1s[row0 + 32], 0.f);
    }
    #pragma unroll
    for (int sp = 0; sp < 5; ++sp) {
        float acc = 0.f;
        #pragma unroll
        for (int i = 0; i < 16; ++i) {
            int row0 = (i & 3) + 8 * (i >> 2) + 4 * hi;
            acc = fmaf(w2s[sp * 64 + row0],      h0[i], acc);
            acc = fmaf(w2s[sp * 64 + row0 + 32], h1[i], acc);
        }
        acc += __shfl_xor(acc, 32, 64);
        if (lane < 32)
            slearn[((size_t)(b * 5 + sp)) * HWSZ + pix0 + px] = acc + rb2s[sp];
    }
}

// ---------------- reduce proxy partials -> per-s score (deterministic)
__global__ void score_kernel(const float* __restrict__ partial,
                             const float* __restrict__ ema_proxy,
                             float* __restrict__ scoreBuf) {
    __shared__ float red[256];
    __shared__ float cur[5];
    int tid = threadIdx.x;
    for (int s = 0; s < 5; ++s) {
        float sum = 0.f;
        for (int i = tid; i < NWID; i += 256) sum += partial[i * 5 + s];
        red[tid] = sum;
        __syncthreads();
        for (int off = 128; off > 0; off >>= 1) {
            if (tid < off) red[tid] += red[tid + off];
            __syncthreads();
        }
        if (tid == 0) cur[s] = red[0] * (1.0f / (64.0f * 2.0f * HWSZ));
        __syncthreads();
    }
    if (tid == 0) {
        float impr[5]; float m = 0.f;
        for (int s = 0; s < 5; ++s) { impr[s] = ema_proxy[s] - cur[s]; m += impr[s]; }
        m *= 0.2f;
        for (int s = 0; s < 5; ++s) {
            float adv = impr[s] - m;
            float c = cur[s];
            float below = fmaxf(0.05f - c, 0.f);
            float above = fmaxf(c - 0.2f, 0.f);
            float band = -(below * below + above * above);
            scoreBuf[s] = 1.0f * adv + 0.5f * band;
        }
    }
}

// ---------------- per-pixel softmax over Sn=5
__global__ void softmax_kernel(const float* __restrict__ slearn,
                               const float* __restrict__ scoreBuf,
                               float* __restrict__ out) {
    int i = blockIdx.x * 256 + threadIdx.x;
    if (i >= 2 * HWSZ) return;
    int b = i / HWSZ, p = i % HWSZ;
    float l[5];
    float mx = -1e30f;
    #pragma unroll
    for (int s = 0; s < 5; ++s) {
        float v = (0.5f * scoreBuf[s] + 0.5f * slearn[((size_t)(b * 5 + s)) * HWSZ + p]) / 0.7f;
        l[s] = v;
        mx = fmaxf(mx, v);
    }
    float sum = 0.f;
    #pragma unroll
    for (int s = 0; s < 5; ++s) { l[s] = expf(l[s] - mx); sum += l[s]; }
    float inv = 1.0f / sum;
    #pragma unroll
    for (int s = 0; s < 5; ++s) out[((size_t)(b * 5 + s)) * HWSZ + p] = l[s] * inv;
}

extern "C" void kernel_launch(void* const* d_in, const int* in_sizes, int n_in,
                              void* d_out, int out_size, void* d_ws, size_t ws_size,
                              hipStream_t stream) {
    const float* S   = (const float*)d_in[0];
    const float* T   = (const float*)d_in[1];
    const float* aw  = (const float*)d_in[2];
    const float* ab  = (const float*)d_in[3];
    const float* rw1 = (const float*)d_in[4];
    const float* rb1 = (const float*)d_in[5];
    const float* rw2 = (const float*)d_in[6];
    const float* rb2 = (const float*)d_in[7];
    const float* mu  = (const float*)d_in[8];
    const float* sg  = (const float*)d_in[9];
    const float* ep  = (const float*)d_in[10];

    float* ws = (float*)d_ws;
    // persistent within launch:
    float* c1f      = ws;                                       // 64
    float* scoreBuf = ws + 64;                                  // 8
    float* partial  = ws + 72;                                  // 11520 (2304*5)
    unsigned short* AfragW  = (unsigned short*)(ws + 11592);    // 40960 ush = 20480 f
    unsigned short* AfragSp = (unsigned short*)(ws + 32072);    // 4096 ush = 2048 f
    float* slearn   = ws + 34120;                               // 368640
    // transient (dead before slearn is written) — aliased inside slearn region:
    float* Dmat     = ws + 34120;                               // 20480
    float* MT       = ws + 54600;                               // 20480
    float* MSp      = ws + 75080;                               // 4096
    float* out = (float*)d_out;

    pre_weights<<<97, 256, 0, stream>>>(rw1, rb1, aw, ab, mu, sg, Dmat, MT, MSp, c1f);
    pre_pack<<<176, 256, 0, stream>>>(Dmat, MT, MSp, AfragW, AfragSp);
    fused_main<<<NWID, 64, 0, stream>>>(S, T, AfragW, AfragSp, c1f, rw2, rb2, slearn, partial);
    score_kernel<<<1, 256, 0, stream>>>(partial, ep, scoreBuf);
    softmax_kernel<<<288, 256, 0, stream>>>(slearn, scoreBuf, out);
}